// Round 5
// baseline (42472.049 us; speedup 1.0000x reference)
//
#include <hip/hip_runtime.h>

// MyRNN: x_{t+1} = x_t + 0.1*(-x_t + (Jij*M) @ sigmoid(x_t) + II[:,t]), x_0 = 0
// out[2048][4096] row-major; col 0 = 0, cols 1..4095 = x_1..x_4095.
//
// Round 5: persistent kernel, J in registers. Sync rebuilt ONLY from
// primitives proven to execute on this HW (rounds 1-2):
//   publish: 1024 packed 8B relaxed atomic stores (write-through) of s_{t+1}
//   guard:   per-wave RELEASE fence (drains own stores) -> __syncthreads ->
//            tid0 stores slot[bid]=t+1 (own 128B line, NO contended RMW)
//   detect:  threads 0..127 spin on slot[tid]==t -- relaxed loads + s_sleep,
//            ***no fences inside any spin loop*** (rounds 3-4 both died after
//            adding fence-per-retry; suspected buffer_inv storm)
//   fetch:   one acquire fence (tid0, between barriers), then plain coalesced
//            float4 loads -- slot==t guarantees data is at the coherence point
// Every spin is capped (~4ms) so a stall yields a finite wrong run, not a hang.
// 0xAA ws-poison = invalid slot values -> no memset, graph-replay idempotent.

#define NN   2048
#define LT   4096
#define NBLK 128
#define TPB  512
#define SPIN_CAP 8192

typedef unsigned long long ull_t;

__global__ __launch_bounds__(TPB, 1)
void rnn_persistent(const float* __restrict__ II,
                    const float* __restrict__ Jij,
                    const float* __restrict__ Mm,
                    float* __restrict__ out,
                    ull_t* __restrict__ spair,     // [2][NN/2] packed {s[2r],s[2r+1]}
                    unsigned* __restrict__ slots)  // [NBLK] @ 32-dword stride
{
    // 64 chunks x 32 floats, pad 33 -> 2-way bank alias (free). Single buffer:
    // the top-of-step barrier separates step-t reads from step-t+1 writes.
    __shared__ float s_lds[64 * 33];

    const int tid  = threadIdx.x;
    const int lane = tid & 63;
    const int wv   = tid >> 6;                 // 0..7
    const int bid  = blockIdx.x;
    const int r0   = bid * 16 + 2 * wv;
    const int r1   = r0 + 1;
    const int colb = lane * 32;

    // ---- one-time: J_eff = Jij * M into registers (2 rows x 32 cols/lane) ----
    float jr0[32], jr1[32];
    {
        const float4* a0 = reinterpret_cast<const float4*>(Jij + (size_t)r0 * NN + colb);
        const float4* m0 = reinterpret_cast<const float4*>(Mm  + (size_t)r0 * NN + colb);
        const float4* a1 = reinterpret_cast<const float4*>(Jij + (size_t)r1 * NN + colb);
        const float4* m1 = reinterpret_cast<const float4*>(Mm  + (size_t)r1 * NN + colb);
#pragma unroll
        for (int k = 0; k < 8; ++k) {
            float4 a = a0[k], m = m0[k];
            jr0[4*k+0] = a.x * m.x; jr0[4*k+1] = a.y * m.y;
            jr0[4*k+2] = a.z * m.z; jr0[4*k+3] = a.w * m.w;
            float4 b = a1[k], n = m1[k];
            jr1[4*k+0] = b.x * n.x; jr1[4*k+1] = b.y * n.y;
            jr1[4*k+2] = b.z * n.z; jr1[4*k+3] = b.w * n.w;
        }
    }

    float x0 = 0.f, x1 = 0.f;   // state, replicated across lanes (bit-identical)
    float vx0 = 0.f, vx1 = 0.f; // deferred-out bank: lane j holds col (cb+j); col 0 stays 0
    float ii0 = 0.f, ii1 = 0.f; // II prefetch: lane l holds II[r, tbase+l]

    for (int t = 0; t < LT - 1; ++t) {
        // refill II prefetch every 64 steps (coalesced; t is 64-aligned here)
        if ((t & 63) == 0) {
            ii0 = II[(size_t)r0 * LT + t + lane];
            ii1 = II[(size_t)r1 * LT + t + lane];
        }

        if (t == 0) {
            // s_0 = sigmoid(0) = 0.5 everywhere: no publish, fill LDS directly.
            const int idx = tid * 4;
            float* p = &s_lds[(idx >> 5) * 33 + (idx & 31)];
            p[0] = 0.5f; p[1] = 0.5f; p[2] = 0.5f; p[3] = 0.5f;
            __syncthreads();
        } else {
            // ---- detect: 128 watchers, one slot each; relaxed loads only ----
            if (tid < NBLK) {
                const unsigned tg = (unsigned)t;
                int iters = 0;
                while (__hip_atomic_load(slots + tid * 32, __ATOMIC_RELAXED,
                                         __HIP_MEMORY_SCOPE_AGENT) != tg) {
                    __builtin_amdgcn_s_sleep(2);
                    if (++iters > SPIN_CAP) break;   // anti-hang insurance
                }
            }
            __syncthreads();
            // one acquire fence per step (proven round-1 pattern): invalidate
            // L1/L2 so the plain loads below refetch from the coherence point
            if (tid == 0) __builtin_amdgcn_fence(__ATOMIC_ACQUIRE, "agent");
            __syncthreads();
            // ---- fetch: plain coalesced 16B loads, no verification needed ----
            const float* sv = reinterpret_cast<const float*>(
                                  spair + (size_t)(t & 1) * (NN / 2));
            float4 v = *reinterpret_cast<const float4*>(sv + tid * 4);
            const int idx = tid * 4;
            float* p = &s_lds[(idx >> 5) * 33 + (idx & 31)];
            p[0] = v.x; p[1] = v.y; p[2] = v.z; p[3] = v.w;
            __syncthreads();
        }

        // ---- dot: 2 rows x 32 cols/lane, butterfly (all lanes get full sums) ----
        float acc0 = 0.f, acc1 = 0.f;
        const float* sl = &s_lds[lane * 33];
#pragma unroll
        for (int j = 0; j < 32; ++j) {
            float sv = sl[j];
            acc0 = fmaf(jr0[j], sv, acc0);
            acc1 = fmaf(jr1[j], sv, acc1);
        }
#pragma unroll
        for (int m = 32; m > 0; m >>= 1) {
            acc0 += __shfl_xor(acc0, m, 64);
            acc1 += __shfl_xor(acc1, m, 64);
        }

        const float It0 = __shfl(ii0, t & 63, 64);
        const float It1 = __shfl(ii1, t & 63, 64);
        x0 = x0 + 0.1f * (-x0 + acc0 + It0);
        x1 = x1 + 0.1f * (-x1 + acc1 + It1);

        const int tp1 = t + 1;
        // deferred coalesced out: lane (tp1&63) banks x; flush 256B/row per 64 steps
        if (lane == (tp1 & 63)) { vx0 = x0; vx1 = x1; }
        if ((tp1 & 63) == 63) {
            const int cb = tp1 & ~63;
            out[(size_t)r0 * LT + cb + lane] = vx0;
            out[(size_t)r1 * LT + cb + lane] = vx1;
        }

        // ---- publish s_{tp1} (needed as input up to t = LT-2) ----
        if (tp1 <= LT - 2) {
            if (lane == 0) {
                const float s0 = 1.f / (1.f + __expf(-x0));
                const float s1 = 1.f / (1.f + __expf(-x1));
                const ull_t pk = ((ull_t)__float_as_uint(s1) << 32)
                               |  (ull_t)__float_as_uint(s0);
                __hip_atomic_store(spair + (size_t)(tp1 & 1) * (NN / 2) + (r0 >> 1),
                                   pk, __ATOMIC_RELAXED, __HIP_MEMORY_SCOPE_AGENT);
            }
            // drain每wave's own stores to the coherence point, THEN signal
            __builtin_amdgcn_fence(__ATOMIC_RELEASE, "agent");
            __syncthreads();
            if (tid == 0) {
                __hip_atomic_store(slots + bid * 32, (unsigned)tp1,
                                   __ATOMIC_RELAXED, __HIP_MEMORY_SCOPE_AGENT);
            }
        }
    }
}

extern "C" void kernel_launch(void* const* d_in, const int* in_sizes, int n_in,
                              void* d_out, int out_size, void* d_ws, size_t ws_size,
                              hipStream_t stream)
{
    const float* II  = (const float*)d_in[0];
    const float* Jij = (const float*)d_in[1];
    const float* Mm  = (const float*)d_in[2];
    float* out = (float*)d_out;

    unsigned char* ws = (unsigned char*)d_ws;
    ull_t*    spair = (ull_t*)(ws + 0);        // 2*1024*8B = 16 KB
    unsigned* slots = (unsigned*)(ws + 16384); // 128 slots * 128B = 16 KB

    // ws re-poisoned to 0xAA before every replay -> slot values are invalid
    // ("not arrived") and spair is guarded by slots; no memset needed.
    rnn_persistent<<<NBLK, TPB, 0, stream>>>(II, Jij, Mm, out, spair, slots);
}

// Round 7
// 14087.973 us; speedup vs baseline: 3.0148x; 3.0148x over previous
//
#include <hip/hip_runtime.h>

// MyRNN: x_{t+1} = x_t + 0.1*(-x_t + (Jij*M) @ sigmoid(x_t) + II[:,t]), x_0 = 0
// out[2048][4096] row-major; col 0 = 0, cols 1..4095 = x_1..x_4095.
//
// Round 7 == round 6 (never ran: GPU acquisition timeout, infra-only failure).
// Design rationale:
//  - NO contended fetch-add chain (round 1's ~5us/step): arrival is a per-block
//    relaxed slot store on a private 128B line; detection is 128 parallel
//    watcher threads (round-5's primitive, which detected promptly).
//  - NO per-wave fence(RELEASE,"agent") (round 5's 2x regression: per-wave L2
//    maintenance storm): release ordering is raw s_waitcnt(0) per wave (pure
//    counter drain) -> __syncthreads -> tid0 signal store. Correct and
//    maintenance-free; also fixes round 1's latent cross-wave ordering race.
//  - Fetch path is exactly round 1's proven pattern: ONE tid0 acquire fence
//    (buffer_inv) per block per step + plain coalesced float4 loads.
//  - No fences anywhere inside spin loops (rounds 3/4 suspect). Monotone
//    signed slot compare (< t): 0xAA poison is negative, producer-ahead safe.

#define NN   2048
#define LT   4096
#define NBLK 128
#define TPB  512
#define SPIN_CAP 100000

typedef unsigned long long ull_t;

__global__ __launch_bounds__(TPB, 1)
void rnn_persistent(const float* __restrict__ II,
                    const float* __restrict__ Jij,
                    const float* __restrict__ Mm,
                    float* __restrict__ out,
                    ull_t* __restrict__ spair,   // [2][NN/2] packed {s[2r],s[2r+1]}
                    int* __restrict__ slots)     // [NBLK] @ 32-int (128B) stride
{
    // 64 chunks x 32 floats, pad 33 -> 2-way bank alias (free). Single buffer:
    // the detect-join barrier separates step-t compute reads from step-t+1 writes.
    __shared__ float s_lds[64 * 33];

    const int tid  = threadIdx.x;
    const int lane = tid & 63;
    const int wv   = tid >> 6;                 // 0..7
    const int bid  = blockIdx.x;
    const int r0   = bid * 16 + 2 * wv;
    const int r1   = r0 + 1;
    const int colb = lane * 32;

    // ---- one-time: J_eff = Jij * M into registers (2 rows x 32 cols/lane) ----
    float jr0[32], jr1[32];
    {
        const float4* a0 = reinterpret_cast<const float4*>(Jij + (size_t)r0 * NN + colb);
        const float4* m0 = reinterpret_cast<const float4*>(Mm  + (size_t)r0 * NN + colb);
        const float4* a1 = reinterpret_cast<const float4*>(Jij + (size_t)r1 * NN + colb);
        const float4* m1 = reinterpret_cast<const float4*>(Mm  + (size_t)r1 * NN + colb);
#pragma unroll
        for (int k = 0; k < 8; ++k) {
            float4 a = a0[k], m = m0[k];
            jr0[4*k+0] = a.x * m.x; jr0[4*k+1] = a.y * m.y;
            jr0[4*k+2] = a.z * m.z; jr0[4*k+3] = a.w * m.w;
            float4 b = a1[k], n = m1[k];
            jr1[4*k+0] = b.x * n.x; jr1[4*k+1] = b.y * n.y;
            jr1[4*k+2] = b.z * n.z; jr1[4*k+3] = b.w * n.w;
        }
    }

    float x0 = 0.f, x1 = 0.f;   // state, replicated across lanes (bit-identical)
    float vx0 = 0.f, vx1 = 0.f; // deferred-out bank: lane j holds col (cb+j); col 0 stays 0
    float ii0 = 0.f, ii1 = 0.f; // II prefetch: lane l holds II[r, tbase+l]

    for (int t = 0; t < LT - 1; ++t) {
        // refill II prefetch every 64 steps (coalesced; consumed via shfl below)
        if ((t & 63) == 0) {
            ii0 = II[(size_t)r0 * LT + t + lane];
            ii1 = II[(size_t)r1 * LT + t + lane];
        }

        if (t == 0) {
            // s_0 = sigmoid(0) = 0.5 everywhere: no exchange needed.
            const int idx = tid * 4;
            float* p = &s_lds[(idx >> 5) * 33 + (idx & 31)];
            p[0] = 0.5f; p[1] = 0.5f; p[2] = 0.5f; p[3] = 0.5f;
            __syncthreads();
        } else {
            // ---- detect: 128 watchers, one private slot line each; no fences ----
            if (tid < NBLK) {
                int iters = 0;
                while (__hip_atomic_load(slots + tid * 32, __ATOMIC_RELAXED,
                                         __HIP_MEMORY_SCOPE_AGENT) < t) {
                    __builtin_amdgcn_s_sleep(1);
                    if (++iters > SPIN_CAP) break;   // anti-hang insurance
                }
            }
            __syncthreads();
            // round-1-proven freshness: ONE acquire fence per block, then plain loads
            if (tid == 0) __builtin_amdgcn_fence(__ATOMIC_ACQUIRE, "agent");
            __syncthreads();
            const float* sv = reinterpret_cast<const float*>(
                                  spair + (size_t)(t & 1) * (NN / 2));
            float4 v = *reinterpret_cast<const float4*>(sv + tid * 4);
            const int idx = tid * 4;
            float* p = &s_lds[(idx >> 5) * 33 + (idx & 31)];
            p[0] = v.x; p[1] = v.y; p[2] = v.z; p[3] = v.w;
            __syncthreads();
        }

        // ---- dot: 2 rows x 32 cols/lane, butterfly (all lanes get full sums) ----
        float acc0 = 0.f, acc1 = 0.f;
        const float* sl = &s_lds[lane * 33];
#pragma unroll
        for (int j = 0; j < 32; ++j) {
            float sv = sl[j];
            acc0 = fmaf(jr0[j], sv, acc0);
            acc1 = fmaf(jr1[j], sv, acc1);
        }
#pragma unroll
        for (int m = 32; m > 0; m >>= 1) {
            acc0 += __shfl_xor(acc0, m, 64);
            acc1 += __shfl_xor(acc1, m, 64);
        }

        const float It0 = __shfl(ii0, t & 63, 64);
        const float It1 = __shfl(ii1, t & 63, 64);
        x0 = x0 + 0.1f * (-x0 + acc0 + It0);
        x1 = x1 + 0.1f * (-x1 + acc1 + It1);

        const int tp1 = t + 1;
        // deferred coalesced out: lane (tp1&63) banks x; flush 256B/row per 64 steps
        if (lane == (tp1 & 63)) { vx0 = x0; vx1 = x1; }
        if ((tp1 & 63) == 63) {
            const int cb = tp1 & ~63;
            out[(size_t)r0 * LT + cb + lane] = vx0;
            out[(size_t)r1 * LT + cb + lane] = vx1;
        }

        // ---- publish s_{tp1} (needed as input up to t = LT-2), then signal ----
        if (tp1 <= LT - 2) {
            if (lane == 0) {
                const float s0 = 1.f / (1.f + __expf(-x0));
                const float s1 = 1.f / (1.f + __expf(-x1));
                const ull_t pk = ((ull_t)__float_as_uint(s1) << 32)
                               |  (ull_t)__float_as_uint(s0);
                __hip_atomic_store(spair + (size_t)(tp1 & 1) * (NN / 2) + (r0 >> 1),
                                   pk, __ATOMIC_RELAXED, __HIP_MEMORY_SCOPE_AGENT);
            }
            // release chain WITHOUT cache maintenance: each wave drains its own
            // outstanding stores (data + any out-flush), then block-barrier,
            // then one relaxed signal store on this block's private line.
            __builtin_amdgcn_s_waitcnt(0);
            __syncthreads();
            if (tid == 0) {
                __hip_atomic_store(slots + bid * 32, tp1,
                                   __ATOMIC_RELAXED, __HIP_MEMORY_SCOPE_AGENT);
            }
        }
    }
}

extern "C" void kernel_launch(void* const* d_in, const int* in_sizes, int n_in,
                              void* d_out, int out_size, void* d_ws, size_t ws_size,
                              hipStream_t stream)
{
    const float* II  = (const float*)d_in[0];
    const float* Jij = (const float*)d_in[1];
    const float* Mm  = (const float*)d_in[2];
    float* out = (float*)d_out;

    unsigned char* ws = (unsigned char*)d_ws;
    ull_t* spair = (ull_t*)(ws + 0);       // 2*1024*8B = 16 KB
    int*   slots = (int*)(ws + 16384);     // 128 slots * 128B = 16 KB

    // ws re-poisoned to 0xAA before every replay -> slot values are 0xAAAAAAAA
    // (negative as int => "not arrived" under the < t check); spair is guarded
    // by slots. No memset needed; graph replay is idempotent.
    rnn_persistent<<<NBLK, TPB, 0, stream>>>(II, Jij, Mm, out, spair, slots);
}

// Round 8
// 13054.100 us; speedup vs baseline: 3.2535x; 1.0792x over previous
//
#include <hip/hip_runtime.h>

// MyRNN: x_{t+1} = x_t + 0.1*(-x_t + (Jij*M) @ sigmoid(x_t) + II[:,t]), x_0 = 0
// out[2048][4096] row-major; col 0 = 0, cols 1..4095 = x_1..x_4095.
//
// Round 8 = round 7 minus the producer ack leg:
//  - publish: {tag,val} 8B relaxed atomic pairs (self-validating, round-2
//    primitive) + slot signal fired IMMEDIATELY (no waitcnt, no barrier -> no
//    compiler-forced vmcnt(0) drain). Data and signal race to L3 concurrently;
//    the signal is only a detection hint, tags carry correctness.
//  - detect: round-7-proven 128 parallel watchers on private 128B slot lines,
//    relaxed loads + s_sleep, no fences in spins, capped.
//  - fetch: ONE tid0 acquire fence + plain coalesced 32B loads, verify 4
//    embedded tags == t; stragglers re-load their own pairs with relaxed
//    ATOMIC loads (coherence-point served, no fence), capped.
//  - ring-2 WAR + exact-tag soundness by transitivity: block publishes t+1
//    only after validating ALL of t => everyone published t => everyone
//    consumed t-1; tags t and t+2 can never coexist for a live consumer.
// 0xAA ws-poison: slots 0xAAAAAAAA < t as int ("not arrived"), tags never
// match -> no memset, graph-replay idempotent.

#define NN   2048
#define LT   4096
#define NBLK 128
#define TPB  512
#define SPIN_CAP 100000

typedef unsigned long long ull_t;

__device__ __forceinline__ ull_t pack_sv(unsigned tag, float v)
{
    return ((ull_t)tag << 32) | (ull_t)__float_as_uint(v);
}

__global__ __launch_bounds__(TPB, 1)
void rnn_persistent(const float* __restrict__ II,
                    const float* __restrict__ Jij,
                    const float* __restrict__ Mm,
                    float* __restrict__ out,
                    ull_t* __restrict__ board,   // [2][NN] {tag,val} pairs
                    int* __restrict__ slots)     // [NBLK] @ 32-int (128B) stride
{
    // 64 chunks x 32 floats, pad 33 -> 2-way bank alias (free). Single buffer:
    // the post-fetch barrier of step t separates compute reads from t+1 writes.
    __shared__ float s_lds[64 * 33];

    const int tid  = threadIdx.x;
    const int lane = tid & 63;
    const int wv   = tid >> 6;                 // 0..7
    const int bid  = blockIdx.x;
    const int r0   = bid * 16 + 2 * wv;
    const int r1   = r0 + 1;
    const int colb = lane * 32;

    // ---- one-time: J_eff = Jij * M into registers (2 rows x 32 cols/lane) ----
    float jr0[32], jr1[32];
    {
        const float4* a0 = reinterpret_cast<const float4*>(Jij + (size_t)r0 * NN + colb);
        const float4* m0 = reinterpret_cast<const float4*>(Mm  + (size_t)r0 * NN + colb);
        const float4* a1 = reinterpret_cast<const float4*>(Jij + (size_t)r1 * NN + colb);
        const float4* m1 = reinterpret_cast<const float4*>(Mm  + (size_t)r1 * NN + colb);
#pragma unroll
        for (int k = 0; k < 8; ++k) {
            float4 a = a0[k], m = m0[k];
            jr0[4*k+0] = a.x * m.x; jr0[4*k+1] = a.y * m.y;
            jr0[4*k+2] = a.z * m.z; jr0[4*k+3] = a.w * m.w;
            float4 b = a1[k], n = m1[k];
            jr1[4*k+0] = b.x * n.x; jr1[4*k+1] = b.y * n.y;
            jr1[4*k+2] = b.z * n.z; jr1[4*k+3] = b.w * n.w;
        }
    }

    float x0 = 0.f, x1 = 0.f;   // state, replicated across lanes (bit-identical)
    float vx0 = 0.f, vx1 = 0.f; // deferred-out bank: lane j holds col (cb+j); col 0 stays 0
    float ii0 = 0.f, ii1 = 0.f; // II prefetch: lane l holds II[r, tbase+l]

    for (int t = 0; t < LT - 1; ++t) {
        // refill II prefetch every 64 steps (coalesced; consumed via shfl below)
        if ((t & 63) == 0) {
            ii0 = II[(size_t)r0 * LT + t + lane];
            ii1 = II[(size_t)r1 * LT + t + lane];
        }

        if (t == 0) {
            // s_0 = sigmoid(0) = 0.5 everywhere: no exchange needed.
            const int idx = tid * 4;
            float* p = &s_lds[(idx >> 5) * 33 + (idx & 31)];
            p[0] = 0.5f; p[1] = 0.5f; p[2] = 0.5f; p[3] = 0.5f;
            __syncthreads();
        } else {
            // ---- detect (hint): 128 watchers, one private slot line each ----
            if (tid < NBLK) {
                int iters = 0;
                while (__hip_atomic_load(slots + tid * 32, __ATOMIC_RELAXED,
                                         __HIP_MEMORY_SCOPE_AGENT) < t) {
                    __builtin_amdgcn_s_sleep(1);
                    if (++iters > SPIN_CAP) break;   // anti-hang insurance
                }
            }
            __syncthreads();
            // freshness: ONE acquire fence per block (round-1/7-proven), then
            // plain coalesced loads of this thread's 4 tagged pairs (32B)
            if (tid == 0) __builtin_amdgcn_fence(__ATOMIC_ACQUIRE, "agent");
            __syncthreads();
            const ull_t* pp = board + (size_t)(t & 1) * NN + tid * 4;
            ull_t a, b, c, d;
            {
                const ulonglong2* q = reinterpret_cast<const ulonglong2*>(pp);
                ulonglong2 u0 = q[0], u1 = q[1];
                a = u0.x; b = u0.y; c = u1.x; d = u1.y;
            }
            // verify embedded tags; rare stragglers re-read via relaxed ATOMIC
            // loads (coherence-point served; round-2 primitive; NO fences)
            const unsigned tg = (unsigned)t;
            int iters = 0;
            while ((unsigned)(a >> 32) != tg || (unsigned)(b >> 32) != tg ||
                   (unsigned)(c >> 32) != tg || (unsigned)(d >> 32) != tg) {
                __builtin_amdgcn_s_sleep(1);
                a = __hip_atomic_load(pp + 0, __ATOMIC_RELAXED, __HIP_MEMORY_SCOPE_AGENT);
                b = __hip_atomic_load(pp + 1, __ATOMIC_RELAXED, __HIP_MEMORY_SCOPE_AGENT);
                c = __hip_atomic_load(pp + 2, __ATOMIC_RELAXED, __HIP_MEMORY_SCOPE_AGENT);
                d = __hip_atomic_load(pp + 3, __ATOMIC_RELAXED, __HIP_MEMORY_SCOPE_AGENT);
                if (++iters > SPIN_CAP) break;       // anti-hang insurance
            }
            const int idx = tid * 4;
            float* p = &s_lds[(idx >> 5) * 33 + (idx & 31)];
            p[0] = __uint_as_float((unsigned)a);
            p[1] = __uint_as_float((unsigned)b);
            p[2] = __uint_as_float((unsigned)c);
            p[3] = __uint_as_float((unsigned)d);
            __syncthreads();
        }

        // ---- dot: 2 rows x 32 cols/lane, butterfly (all lanes get full sums) ----
        float acc0 = 0.f, acc1 = 0.f;
        const float* sl = &s_lds[lane * 33];
#pragma unroll
        for (int j = 0; j < 32; ++j) {
            float sv = sl[j];
            acc0 = fmaf(jr0[j], sv, acc0);
            acc1 = fmaf(jr1[j], sv, acc1);
        }
#pragma unroll
        for (int m = 32; m > 0; m >>= 1) {
            acc0 += __shfl_xor(acc0, m, 64);
            acc1 += __shfl_xor(acc1, m, 64);
        }

        const float It0 = __shfl(ii0, t & 63, 64);
        const float It1 = __shfl(ii1, t & 63, 64);
        x0 = x0 + 0.1f * (-x0 + acc0 + It0);
        x1 = x1 + 0.1f * (-x1 + acc1 + It1);

        const int tp1 = t + 1;
        // deferred coalesced out: lane (tp1&63) banks x; flush 256B/row per 64 steps
        if (lane == (tp1 & 63)) { vx0 = x0; vx1 = x1; }
        if ((tp1 & 63) == 63) {
            const int cb = tp1 & ~63;
            out[(size_t)r0 * LT + cb + lane] = vx0;
            out[(size_t)r1 * LT + cb + lane] = vx1;
        }

        // ---- publish s_{tp1}: tagged pairs + immediate hint signal ----
        // No waitcnt, no barrier: data and signal propagate concurrently;
        // consumers' tag verification covers any reordering window.
        if (tp1 <= LT - 2) {
            if (lane == 0) {
                const float s0 = 1.f / (1.f + __expf(-x0));
                const float s1 = 1.f / (1.f + __expf(-x1));
                ull_t* wr = board + (size_t)(tp1 & 1) * NN;
                __hip_atomic_store(wr + r0, pack_sv((unsigned)tp1, s0),
                                   __ATOMIC_RELAXED, __HIP_MEMORY_SCOPE_AGENT);
                __hip_atomic_store(wr + r1, pack_sv((unsigned)tp1, s1),
                                   __ATOMIC_RELAXED, __HIP_MEMORY_SCOPE_AGENT);
            }
            if (tid == 0) {
                __hip_atomic_store(slots + bid * 32, tp1,
                                   __ATOMIC_RELAXED, __HIP_MEMORY_SCOPE_AGENT);
            }
        }
    }
}

extern "C" void kernel_launch(void* const* d_in, const int* in_sizes, int n_in,
                              void* d_out, int out_size, void* d_ws, size_t ws_size,
                              hipStream_t stream)
{
    const float* II  = (const float*)d_in[0];
    const float* Jij = (const float*)d_in[1];
    const float* Mm  = (const float*)d_in[2];
    float* out = (float*)d_out;

    unsigned char* ws = (unsigned char*)d_ws;
    ull_t* board = (ull_t*)(ws + 0);       // 2*2048*8B = 32 KB tagged pairs
    int*   slots = (int*)(ws + 32768);     // 128 slots * 128B = 16 KB

    // ws re-poisoned to 0xAA before every replay -> slots read 0xAAAAAAAA
    // (negative => "not arrived") and board tags never match; no memset needed.
    rnn_persistent<<<NBLK, TPB, 0, stream>>>(II, Jij, Mm, out, board, slots);
}

// Round 9
// 12283.692 us; speedup vs baseline: 3.4576x; 1.0627x over previous
//
#include <hip/hip_runtime.h>

// MyRNN: x_{t+1} = x_t + 0.1*(-x_t + (Jij*M) @ sigmoid(x_t) + II[:,t]), x_0 = 0
// out[2048][4096] row-major; col 0 = 0, cols 1..4095 = x_1..x_4095.
//
// Round 9 = round 8 with HALF the sync participants (contention probe):
//   64 blocks x 1024 threads (was 128 x 512). Same 2 rows/wave, same 64
//   J-VGPRs/lane, same compute. Slot lines 128->64, pollers-per-line 128->64,
//   signals-to-await 128->64, board fetch 2MB->1MB/step.
// Theory: detect phase is dominated by same-line atomic-load queueing at the
// coherence point (round-1 lesson: ~30-40ns per same-line op); halving both
// line poller count and signal count should halve detection cost.
// All round-8 primitives unchanged: tagged self-validating pairs, immediate
// hint signal (no producer ack), fence-free spins, ONE tid0 acquire fence,
// deferred coalesced out, II register prefetch. 0xAA poison = invalid tags.

#define NN   2048
#define LT   4096
#define NBLK 64
#define TPB  1024
#define SPIN_CAP 100000

typedef unsigned long long ull_t;

__device__ __forceinline__ ull_t pack_sv(unsigned tag, float v)
{
    return ((ull_t)tag << 32) | (ull_t)__float_as_uint(v);
}

__global__ __launch_bounds__(TPB, 1)
void rnn_persistent(const float* __restrict__ II,
                    const float* __restrict__ Jij,
                    const float* __restrict__ Mm,
                    float* __restrict__ out,
                    ull_t* __restrict__ board,   // [2][NN] {tag,val} pairs
                    int* __restrict__ slots)     // [NBLK] @ 32-int (128B) stride
{
    // 64 chunks x 32 floats, pad 33 -> 2-way bank alias (free). Single buffer:
    // the post-fetch barrier of step t separates compute reads from t+1 writes.
    __shared__ float s_lds[64 * 33];

    const int tid  = threadIdx.x;
    const int lane = tid & 63;
    const int wv   = tid >> 6;                 // 0..15
    const int bid  = blockIdx.x;
    const int r0   = bid * 32 + 2 * wv;        // 32 rows per block
    const int r1   = r0 + 1;
    const int colb = lane * 32;

    // ---- one-time: J_eff = Jij * M into registers (2 rows x 32 cols/lane) ----
    float jr0[32], jr1[32];
    {
        const float4* a0 = reinterpret_cast<const float4*>(Jij + (size_t)r0 * NN + colb);
        const float4* m0 = reinterpret_cast<const float4*>(Mm  + (size_t)r0 * NN + colb);
        const float4* a1 = reinterpret_cast<const float4*>(Jij + (size_t)r1 * NN + colb);
        const float4* m1 = reinterpret_cast<const float4*>(Mm  + (size_t)r1 * NN + colb);
#pragma unroll
        for (int k = 0; k < 8; ++k) {
            float4 a = a0[k], m = m0[k];
            jr0[4*k+0] = a.x * m.x; jr0[4*k+1] = a.y * m.y;
            jr0[4*k+2] = a.z * m.z; jr0[4*k+3] = a.w * m.w;
            float4 b = a1[k], n = m1[k];
            jr1[4*k+0] = b.x * n.x; jr1[4*k+1] = b.y * n.y;
            jr1[4*k+2] = b.z * n.z; jr1[4*k+3] = b.w * n.w;
        }
    }

    float x0 = 0.f, x1 = 0.f;   // state, replicated across lanes (bit-identical)
    float vx0 = 0.f, vx1 = 0.f; // deferred-out bank: lane j holds col (cb+j); col 0 stays 0
    float ii0 = 0.f, ii1 = 0.f; // II prefetch: lane l holds II[r, tbase+l]

    for (int t = 0; t < LT - 1; ++t) {
        // refill II prefetch every 64 steps (coalesced; consumed via shfl below)
        if ((t & 63) == 0) {
            ii0 = II[(size_t)r0 * LT + t + lane];
            ii1 = II[(size_t)r1 * LT + t + lane];
        }

        if (t == 0) {
            // s_0 = sigmoid(0) = 0.5 everywhere: no exchange needed.
            const int idx = tid * 2;
            float* p = &s_lds[(idx >> 5) * 33 + (idx & 31)];
            p[0] = 0.5f; p[1] = 0.5f;
            __syncthreads();
        } else {
            // ---- detect (hint): 64 watchers, one private slot line each ----
            if (tid < NBLK) {
                int iters = 0;
                while (__hip_atomic_load(slots + tid * 32, __ATOMIC_RELAXED,
                                         __HIP_MEMORY_SCOPE_AGENT) < t) {
                    __builtin_amdgcn_s_sleep(1);
                    if (++iters > SPIN_CAP) break;   // anti-hang insurance
                }
            }
            __syncthreads();
            // freshness: ONE acquire fence per block, then plain coalesced
            // loads of this thread's 2 tagged pairs (16B)
            if (tid == 0) __builtin_amdgcn_fence(__ATOMIC_ACQUIRE, "agent");
            __syncthreads();
            const ull_t* pp = board + (size_t)(t & 1) * NN + tid * 2;
            ull_t a, b;
            {
                ulonglong2 u0 = *reinterpret_cast<const ulonglong2*>(pp);
                a = u0.x; b = u0.y;
            }
            // verify embedded tags; rare stragglers re-read via relaxed ATOMIC
            // loads (coherence-point served; NO fences in the retry loop)
            const unsigned tg = (unsigned)t;
            int iters = 0;
            while ((unsigned)(a >> 32) != tg || (unsigned)(b >> 32) != tg) {
                __builtin_amdgcn_s_sleep(1);
                a = __hip_atomic_load(pp + 0, __ATOMIC_RELAXED, __HIP_MEMORY_SCOPE_AGENT);
                b = __hip_atomic_load(pp + 1, __ATOMIC_RELAXED, __HIP_MEMORY_SCOPE_AGENT);
                if (++iters > SPIN_CAP) break;       // anti-hang insurance
            }
            const int idx = tid * 2;
            float* p = &s_lds[(idx >> 5) * 33 + (idx & 31)];
            p[0] = __uint_as_float((unsigned)a);
            p[1] = __uint_as_float((unsigned)b);
            __syncthreads();
        }

        // ---- dot: 2 rows x 32 cols/lane, butterfly (all lanes get full sums) ----
        float acc0 = 0.f, acc1 = 0.f;
        const float* sl = &s_lds[lane * 33];
#pragma unroll
        for (int j = 0; j < 32; ++j) {
            float sv = sl[j];
            acc0 = fmaf(jr0[j], sv, acc0);
            acc1 = fmaf(jr1[j], sv, acc1);
        }
#pragma unroll
        for (int m = 32; m > 0; m >>= 1) {
            acc0 += __shfl_xor(acc0, m, 64);
            acc1 += __shfl_xor(acc1, m, 64);
        }

        const float It0 = __shfl(ii0, t & 63, 64);
        const float It1 = __shfl(ii1, t & 63, 64);
        x0 = x0 + 0.1f * (-x0 + acc0 + It0);
        x1 = x1 + 0.1f * (-x1 + acc1 + It1);

        const int tp1 = t + 1;
        // deferred coalesced out: lane (tp1&63) banks x; flush 256B/row per 64 steps
        if (lane == (tp1 & 63)) { vx0 = x0; vx1 = x1; }
        if ((tp1 & 63) == 63) {
            const int cb = tp1 & ~63;
            out[(size_t)r0 * LT + cb + lane] = vx0;
            out[(size_t)r1 * LT + cb + lane] = vx1;
        }

        // ---- publish s_{tp1}: tagged pairs + immediate hint signal ----
        // No waitcnt, no barrier: data and signal propagate concurrently;
        // consumers' tag verification covers any reordering window.
        if (tp1 <= LT - 2) {
            if (lane == 0) {
                const float s0 = 1.f / (1.f + __expf(-x0));
                const float s1 = 1.f / (1.f + __expf(-x1));
                ull_t* wr = board + (size_t)(tp1 & 1) * NN;
                __hip_atomic_store(wr + r0, pack_sv((unsigned)tp1, s0),
                                   __ATOMIC_RELAXED, __HIP_MEMORY_SCOPE_AGENT);
                __hip_atomic_store(wr + r1, pack_sv((unsigned)tp1, s1),
                                   __ATOMIC_RELAXED, __HIP_MEMORY_SCOPE_AGENT);
            }
            if (tid == 0) {
                __hip_atomic_store(slots + bid * 32, tp1,
                                   __ATOMIC_RELAXED, __HIP_MEMORY_SCOPE_AGENT);
            }
        }
    }
}

extern "C" void kernel_launch(void* const* d_in, const int* in_sizes, int n_in,
                              void* d_out, int out_size, void* d_ws, size_t ws_size,
                              hipStream_t stream)
{
    const float* II  = (const float*)d_in[0];
    const float* Jij = (const float*)d_in[1];
    const float* Mm  = (const float*)d_in[2];
    float* out = (float*)d_out;

    unsigned char* ws = (unsigned char*)d_ws;
    ull_t* board = (ull_t*)(ws + 0);       // 2*2048*8B = 32 KB tagged pairs
    int*   slots = (int*)(ws + 32768);     // 64 slots * 128B = 8 KB

    // ws re-poisoned to 0xAA before every replay -> slots read 0xAAAAAAAA
    // (negative => "not arrived") and board tags never match; no memset needed.
    rnn_persistent<<<NBLK, TPB, 0, stream>>>(II, Jij, Mm, out, board, slots);
}